// Round 1
// baseline (5348.797 us; speedup 1.0000x reference)
//
#include <hip/hip_runtime.h>

// ---------------- problem constants ----------------
#define NROI  100
#define NB    4          // 400/100 diagonal blocks
#define NEDGE 160000
#define RESN  1000
#define SAMP  50
#define BREP  8          // batch tiling (B=8)
#define MDEG  44         // effective polynomial rank cutoff (tunable)
#define NMODE (MDEG + 1)
#define BIGF  1.0e9f
#define PAIR_CAP 5056    // >= 100*99/2 - 99 masked pairs

// ---------------- static device workspace (no hipMalloc allowed) ----------------
__device__ int   g_cr[NEDGE];
__device__ int   g_cc[NEDGE];
__device__ float g_ca[NEDGE];
__device__ int   g_ccount;

__device__ float g_D[NB * NROI * NROI];
__device__ float g_death1[NB * NROI * NROI];
__device__ unsigned char g_mst[NB * NROI * NROI];
__device__ float g_betti[NB * RESN];
__device__ float g_pb[NB][PAIR_CAP];
__device__ float g_pd[NB][PAIR_CAP];
__device__ int   g_pcnt[NB];
__device__ float g_smin[NB], g_smax[NB];
__device__ double g_q[NMODE][RESN];   // orthonormal poly basis values
__device__ double g_qd[NMODE][RESN];  // derivatives d/dx

// ---------------- helpers ----------------
__device__ inline double wave_sum_f64(double p) {
    for (int off = 32; off > 0; off >>= 1) p += __shfl_xor(p, off, 64);
    return p;
}

// ---------------- 1) stable, order-preserving compaction of diagonal-block edges ----------------
__global__ void __launch_bounds__(1024) k_compact(const int* ei, const float* ea) {
    __shared__ int pred[1024];
    __shared__ int base;
    const int tid = threadIdx.x;
    if (tid == 0) base = 0;
    __syncthreads();
    for (int start = 0; start < NEDGE; start += 1024) {
        const int e = start + tid;
        int r = 0, c = 0, p = 0; float a = 0.f;
        if (e < NEDGE) {
            r = ei[e]; c = ei[NEDGE + e]; a = ea[e];
            p = ((r / NROI) == (c / NROI)) ? 1 : 0;
        }
        pred[tid] = p;
        __syncthreads();
        // Hillis-Steele inclusive scan
        for (int off = 1; off < 1024; off <<= 1) {
            int v = (tid >= off) ? pred[tid - off] : 0;
            __syncthreads();
            pred[tid] += v;
            __syncthreads();
        }
        if (p) {
            const int pos = base + pred[tid] - 1;
            g_cr[pos] = r; g_cc[pos] = c; g_ca[pos] = a;
        }
        __syncthreads();
        if (tid == 0) base += pred[1023];
        __syncthreads();
    }
    if (tid == 0) g_ccount = base;
}

// ---------------- 2) D = max(1 - adj, 0); f32 sums in exact edge order ----------------
__global__ void k_build_D() {
    const int tid = blockIdx.x * blockDim.x + threadIdx.x;
    if (tid >= NB * NROI * NROI) return;
    const int b  = tid / (NROI * NROI);
    const int ij = tid % (NROI * NROI);
    const int row = b * NROI + ij / NROI;
    const int col = b * NROI + ij % NROI;
    const int n = g_ccount;
    float s = 0.f;  // sequential f32 accumulation in edge order (matches np.add.at)
    for (int e = 0; e < n; ++e) {
        if (g_cr[e] == row && g_cc[e] == col) s += g_ca[e];
    }
    const float d = 1.f - s;
    g_D[tid] = d > 0.f ? d : 0.f;
}

// ---------------- 3) Prim MST (exact jnp.argmin first-index tie-break) + betti ----------------
__global__ void __launch_bounds__(128) k_prim() {
    const int b = blockIdx.x;
    const int t = threadIdx.x;
    __shared__ float mind[NROI];
    __shared__ int   parent[NROI];
    __shared__ unsigned char intree[NROI];
    __shared__ float sval[128];
    __shared__ int   sidx[128];
    __shared__ float deaths[NROI - 1];
    __shared__ int   us[NROI - 1], vs[NROI - 1];
    const float* Db = g_D + b * NROI * NROI;
    if (t < NROI) {
        mind[t]   = Db[t];          // D[0][t]
        parent[t] = 0;
        intree[t] = (t == 0) ? 1 : 0;
    }
    __syncthreads();
    for (int step = 0; step < NROI - 1; ++step) {
        float v = 3.0e38f; int idx = (1 << 20);
        if (t < NROI) { v = intree[t] ? BIGF : mind[t]; idx = t; }
        sval[t] = v; sidx[t] = idx;
        __syncthreads();
        for (int off = 64; off > 0; off >>= 1) {
            if (t < off) {
                const float v2 = sval[t + off]; const int i2 = sidx[t + off];
                if (v2 < sval[t] || (v2 == sval[t] && i2 < sidx[t])) { sval[t] = v2; sidx[t] = i2; }
            }
            __syncthreads();
        }
        const int j = sidx[0];
        if (t == 0) {
            deaths[step] = sval[0];
            us[step] = parent[j];
            vs[step] = j;
            intree[j] = 1;
        }
        __syncthreads();
        if (t < NROI && !intree[t]) {
            const float dj = Db[j * NROI + t];
            if (dj < mind[t]) { mind[t] = dj; parent[t] = j; }  // strict <, as reference
        }
        __syncthreads();
    }
    // MST adjacency (symmetric)
    if (t < NROI) {
        unsigned char* m = g_mst + b * NROI * NROI + t * NROI;
        for (int jj = 0; jj < NROI; ++jj) m[jj] = 0;
    }
    __syncthreads();
    if (t < NROI - 1) {
        const int u = us[t], w = vs[t];
        g_mst[b * NROI * NROI + u * NROI + w] = 1;
        g_mst[b * NROI * NROI + w * NROI + u] = 1;
    }
    // dmax over deaths
    sval[t] = (t < NROI - 1) ? deaths[t] : -1.0f;
    __syncthreads();
    for (int off = 64; off > 0; off >>= 1) {
        if (t < off) sval[t] = fmaxf(sval[t], sval[t + off]);
        __syncthreads();
    }
    const float dmax = sval[0];
    const float stepg = dmax / 999.0f;  // f32 linspace step, start = 0
    for (int tt = t; tt < RESN; tt += 128) {
        const float g = (tt == RESN - 1) ? dmax : (float)tt * stepg;
        int cnt = 0;
        for (int s2 = 0; s2 < NROI - 1; ++s2) cnt += (g < deaths[s2]) ? 1 : 0;
        g_betti[b * RESN + tt] = (float)cnt;
    }
}

// ---------------- 4) H1 deaths: T[i,j] = min_k!=i,j max(D[i,k],D[j,k]); death1 = max(D,T) ----------------
__global__ void k_death1() {
    const int tid = blockIdx.x * blockDim.x + threadIdx.x;
    if (tid >= NB * NROI * NROI) return;
    const int b  = tid / (NROI * NROI);
    const int ij = tid % (NROI * NROI);
    const int i = ij / NROI, j = ij % NROI;
    const float* Db = g_D + b * NROI * NROI;
    const float* ri = Db + i * NROI;
    const float* rj = Db + j * NROI;
    float Tm = BIGF;
    for (int k = 0; k < NROI; ++k) {
        const float m = (k == i || k == j) ? BIGF : fmaxf(ri[k], rj[k]);
        Tm = fminf(Tm, m);
    }
    g_death1[tid] = fmaxf(Db[ij], Tm);
}

// ---------------- 5) masked pair compaction + smin/smax ----------------
__global__ void __launch_bounds__(256) k_minmax() {
    const int b = blockIdx.x, t = threadIdx.x;
    __shared__ float smn[256], smx[256];
    if (t == 0) g_pcnt[b] = 0;
    __syncthreads();
    float mn = BIGF, mx = -BIGF;
    for (int e = t; e < NROI * NROI; e += 256) {
        const int i = e / NROI, j = e % NROI;
        if (i < j && !g_mst[b * NROI * NROI + e]) {
            const float bv = g_D[b * NROI * NROI + e];
            const float dv = g_death1[b * NROI * NROI + e];
            mn = fminf(mn, bv);
            mx = fmaxf(mx, dv);
            const int pos = atomicAdd(&g_pcnt[b], 1);
            g_pb[b][pos] = bv;
            g_pd[b][pos] = dv;
        }
    }
    smn[t] = mn; smx[t] = mx;
    __syncthreads();
    for (int off = 128; off > 0; off >>= 1) {
        if (t < off) { smn[t] = fminf(smn[t], smn[t + off]); smx[t] = fmaxf(smx[t], smx[t + off]); }
        __syncthreads();
    }
    if (t == 0) { g_smin[b] = smn[0]; g_smax[b] = smx[0]; }
}

// ---------------- 6) persistence landscape: top-5 tent mean per grid point ----------------
__global__ void __launch_bounds__(256) k_land(float* __restrict__ out) {
    const int b = blockIdx.x, t = threadIdx.x;
    __shared__ float pb[PAIR_CAP], pd[PAIR_CAP];
    const int cnt = g_pcnt[b];
    const float smn = g_smin[b], smx = g_smax[b];
    for (int e = t; e < cnt; e += 256) { pb[e] = g_pb[b][e]; pd[e] = g_pd[b][e]; }
    __syncthreads();
    const float stepg = (smx - smn) / 999.0f;
    const float SQ2 = 1.41421356f;  // f32 sqrt(2), as reference
    for (int tt = t; tt < RESN; tt += 256) {
        const float g = (tt == RESN - 1) ? smx : smn + (float)tt * stepg;
        float t5[5] = {0.f, 0.f, 0.f, 0.f, 0.f};  // tents >= 0; thousands of zero tents exist
        for (int e = 0; e < cnt; ++e) {
            float v = fminf(g - pb[e], pd[e] - g);
            v = v > 0.f ? v : 0.f;
            v *= SQ2;
            if (v > t5[4]) {
                t5[4] = v;
                for (int z = 4; z > 0 && t5[z] > t5[z - 1]; --z) {
                    const float tmp = t5[z - 1]; t5[z - 1] = t5[z]; t5[z] = tmp;
                }
            }
        }
        const float land = (t5[0] + t5[1] + t5[2] + t5[3] + t5[4]) / 5.0f;
        for (int rep = 0; rep < BREP; ++rep)
            out[(rep * NB + b) * RESN + tt] = land;
    }
}

// ---------------- 7) orthonormal polynomial basis (Lanczos on diag(x), full reorth, f64) ----------------
__global__ void __launch_bounds__(1024) k_basis() {
    const int t = threadIdx.x;
    const int lane = t & 63, wv = t >> 6;  // 16 waves
    __shared__ double xs[RESN];
    __shared__ double w[RESN], dwv[RESN];
    __shared__ double cj[NMODE], ctot[NMODE];
    __shared__ double red[16];
    if (t < RESN) {
        xs[t] = (2.0 * (double)t - 999.0) / 999.0;  // exactly antisymmetric grid
        const double q0 = 1.0 / sqrt(1000.0);
        g_q[0][t] = q0;
        g_qd[0][t] = 0.0;
    }
    __syncthreads();
    for (int k = 0; k < MDEG; ++k) {
        if (t < RESN) {
            w[t]   = xs[t] * g_q[k][t];
            dwv[t] = g_q[k][t] + xs[t] * g_qd[k][t];
        }
        if (t < NMODE) ctot[t] = 0.0;
        __syncthreads();
        for (int round = 0; round < 2; ++round) {   // CGS twice == stable
            for (int j = wv; j <= k; j += 16) {
                double p = 0.0;
                for (int tt = lane; tt < RESN; tt += 64) p += w[tt] * g_q[j][tt];
                p = wave_sum_f64(p);
                if (lane == 0) cj[j] = p;
            }
            __syncthreads();
            if (t < RESN) {
                double acc = w[t];
                for (int j = 0; j <= k; ++j) acc -= cj[j] * g_q[j][t];
                w[t] = acc;
            }
            if (t <= k) ctot[t] += cj[t];
            __syncthreads();
        }
        if (t < RESN) {
            double acc = dwv[t];
            for (int j = 0; j <= k; ++j) acc -= ctot[j] * g_qd[j][t];
            dwv[t] = acc;
        }
        // norm of w
        double p = 0.0;
        for (int tt = t; tt < RESN; tt += 1024) p += w[tt] * w[tt];
        p = wave_sum_f64(p);
        if (lane == 0) red[wv] = p;
        __syncthreads();
        if (t == 0) {
            double s = 0.0;
            for (int z = 0; z < 16; ++z) s += red[z];
            red[0] = sqrt(s);
        }
        __syncthreads();
        const double beta = red[0];
        if (t < RESN) {
            g_q[k + 1][t]  = w[t] / beta;
            g_qd[k + 1][t] = dwv[t] / beta;
        }
        __syncthreads();
    }
}

// ---------------- 8) fit: project betti onto basis; emit yvals and |derivative|*scale ----------------
__global__ void __launch_bounds__(256) k_fit(float* __restrict__ out) {
    const int b = blockIdx.x, t = threadIdx.x;
    const int lane = t & 63, wv = t >> 6;  // 4 waves
    __shared__ double dk[NMODE];
    __shared__ float  bet[RESN];
    for (int tt = t; tt < RESN; tt += 256) bet[tt] = g_betti[b * RESN + tt];
    __syncthreads();
    for (int k = wv; k < NMODE; k += 4) {
        double p = 0.0;
        for (int tt = lane; tt < RESN; tt += 64) p += (double)bet[tt] * g_q[k][tt];
        p = wave_sum_f64(p);
        if (lane == 0) dk[k] = p;
    }
    __syncthreads();
    const double scale = 2.0 / 999.0;
    float* oy = out + BREP * NB * RESN;
    float* od = out + 2 * BREP * NB * RESN;
    for (int tt = t; tt < RESN; tt += 256) {
        double y = 0.0, d = 0.0;
        for (int k = 0; k < NMODE; ++k) {
            y += dk[k] * g_q[k][tt];
            d += dk[k] * g_qd[k][tt];
        }
        const float yv = (float)y;
        const float fd = (float)(fabs(d) * scale);
        for (int rep = 0; rep < BREP; ++rep) {
            oy[(rep * NB + b) * RESN + tt] = yv;
            if (tt >= SAMP && tt < RESN - SAMP)
                od[(rep * NB + b) * (RESN - 2 * SAMP) + (tt - SAMP)] = fd;
        }
    }
}

// ---------------- launcher ----------------
extern "C" void kernel_launch(void* const* d_in, const int* in_sizes, int n_in,
                              void* d_out, int out_size, void* d_ws, size_t ws_size,
                              hipStream_t stream) {
    const int*   ei  = (const int*)d_in[1];    // edge_index (2, 160000)
    const float* ea  = (const float*)d_in[2];  // edge_attr  (160000, 1)
    float*       out = (float*)d_out;          // [land 32x1000 | yvals 32x1000 | fderiv 32x900]

    k_compact<<<1, 1024, 0, stream>>>(ei, ea);
    k_build_D<<<(NB * NROI * NROI + 255) / 256, 256, 0, stream>>>();
    k_prim<<<NB, 128, 0, stream>>>();
    k_death1<<<(NB * NROI * NROI + 255) / 256, 256, 0, stream>>>();
    k_minmax<<<NB, 256, 0, stream>>>();
    k_land<<<NB, 256, 0, stream>>>(out);
    k_basis<<<1, 1024, 0, stream>>>();
    k_fit<<<NB, 256, 0, stream>>>(out);
}

// Round 2
// 248.701 us; speedup vs baseline: 21.5070x; 21.5070x over previous
//
#include <hip/hip_runtime.h>

// ---------------- problem constants ----------------
#define NROI  100
#define NB    4          // 400/100 diagonal blocks
#define NEDGE 160000
#define RESN  1000
#define SAMP  50
#define BREP  8          // batch tiling (B=8)
#define MDEG  44         // effective polynomial rank cutoff
#define NMODE (MDEG + 1)
#define BIGF  1.0e9f
#define PAIR_CAP 5056    // >= 100*99/2 - 99 masked pairs

// ---------------- static device workspace ----------------
__device__ float g_adj[NB * NROI * NROI];
__device__ float g_D[NB * NROI * NROI];
__device__ float g_death1[NB * NROI * NROI];
__device__ float g_betti[NB * RESN];
__device__ float g_pb[NB][PAIR_CAP];
__device__ float g_pd[NB][PAIR_CAP];
__device__ int   g_pcnt[NB];
__device__ float g_smin[NB], g_smax[NB];
__device__ int   g_bnz;              // any nonzero betti? (gates k_basis)
__device__ double g_q[NMODE][RESN];  // orthonormal poly basis values
__device__ double g_qd[NMODE][RESN]; // derivatives d/dx

// ---------------- helpers ----------------
__device__ inline double wave_sum_f64(double p) {
    for (int off = 32; off > 0; off >>= 1) p += __shfl_xor(p, off, 64);
    return p;
}

// ---------------- 1) zero accumulators ----------------
__global__ void k_zero() {
    const int tid = blockIdx.x * blockDim.x + threadIdx.x;
    if (tid < NB * NROI * NROI) g_adj[tid] = 0.f;
    if (tid == 0) g_bnz = 0;
}

// ---------------- 2) scatter-add diagonal-block edges ----------------
__global__ void k_scatter(const int* __restrict__ ei, const float* __restrict__ ea) {
    const int e = blockIdx.x * blockDim.x + threadIdx.x;
    if (e >= NEDGE) return;
    const int r = ei[e], c = ei[NEDGE + e];
    const int br = r / NROI, bc = c / NROI;
    if (br == bc)
        atomicAdd(&g_adj[br * NROI * NROI + (r - br * NROI) * NROI + (c - bc * NROI)], ea[e]);
}

// ---------------- 3) D = max(1 - adj, 0) ----------------
__global__ void k_transform() {
    const int tid = blockIdx.x * blockDim.x + threadIdx.x;
    if (tid >= NB * NROI * NROI) return;
    const float d = 1.f - g_adj[tid];
    g_D[tid] = d > 0.f ? d : 0.f;
}

// ---------------- 4) H1 deaths: T[i,j] = min_k!=i,j max(D[i,k],D[j,k]); death1 = max(D,T) ----------------
__global__ void k_death1() {
    const int tid = blockIdx.x * blockDim.x + threadIdx.x;
    if (tid >= NB * NROI * NROI) return;
    const int b  = tid / (NROI * NROI);
    const int ij = tid % (NROI * NROI);
    const int i = ij / NROI, j = ij % NROI;
    const float* Db = g_D + b * NROI * NROI;
    const float* ri = Db + i * NROI;
    const float* rj = Db + j * NROI;
    float Tm = BIGF;
    for (int k = 0; k < NROI; ++k) {
        const float m = (k == i || k == j) ? BIGF : fmaxf(ri[k], rj[k]);
        Tm = fminf(Tm, m);
    }
    g_death1[tid] = fmaxf(Db[ij], Tm);
}

// ---------------- 5) single-wave Prim (exact first-index argmin tie-break)
//                    + fused mst mask, pair compaction, smin/smax, betti ----------------
__global__ void __launch_bounds__(64) k_prim() {
    const int b = blockIdx.x, lane = threadIdx.x;
    const float* Db = g_D + b * NROI * NROI;
    __shared__ float deaths[NROI - 1];
    __shared__ short us_s[NROI - 1], vs_s[NROI - 1];
    __shared__ unsigned char mstL[NROI * NROI];
    __shared__ int cntL;
    const int i1 = 64 + lane;
    const bool has1 = (i1 < NROI);
    float mind0 = Db[lane];                 // D[0][lane]
    float mind1 = has1 ? Db[i1] : BIGF;
    int par0 = 0, par1 = 0;
    bool in0 = (lane == 0), in1 = false;
    for (int step = 0; step < NROI - 1; ++step) {
        float v0 = in0 ? BIGF : mind0;
        float v1 = (has1 && !in1) ? mind1 : BIGF;
        float v; int idx;
        if (v0 <= v1) { v = v0; idx = lane; } else { v = v1; idx = i1; }
        #pragma unroll
        for (int off = 1; off < 64; off <<= 1) {
            const float ov = __shfl_xor(v, off, 64);
            const int   oi = __shfl_xor(idx, off, 64);
            if (ov < v || (ov == v && oi < idx)) { v = ov; idx = oi; }
        }
        const int j = idx;                   // uniform across lanes
        const int pj0 = __shfl(par0, j & 63, 64);
        const int pj1 = __shfl(par1, j & 63, 64);
        const int u = (j < 64) ? pj0 : pj1;
        if (lane == 0) { deaths[step] = v; us_s[step] = (short)u; vs_s[step] = (short)j; }
        if (lane == j) in0 = true;
        if (i1 == j)   in1 = true;
        const float dj0 = Db[j * NROI + lane];
        if (!in0 && dj0 < mind0) { mind0 = dj0; par0 = j; }   // strict <, as reference
        if (has1) {
            const float dj1 = Db[j * NROI + i1];
            if (!in1 && dj1 < mind1) { mind1 = dj1; par1 = j; }
        }
    }
    // LDS mst bitmap
    for (int e = lane; e < NROI * NROI; e += 64) mstL[e] = 0;
    if (lane == 0) cntL = 0;
    __syncthreads();
    for (int s = lane; s < NROI - 1; s += 64) {
        const int u = us_s[s], w = vs_s[s];
        mstL[u * NROI + w] = 1;
        mstL[w * NROI + u] = 1;
    }
    __syncthreads();
    // masked pair compaction + smin/smax
    float mn = BIGF, mx = -BIGF;
    for (int e = lane; e < NROI * NROI; e += 64) {
        const int i = e / NROI, jj = e % NROI;
        if (i < jj && !mstL[e]) {
            const float bv = Db[e];
            const float dv = g_death1[b * NROI * NROI + e];
            mn = fminf(mn, bv); mx = fmaxf(mx, dv);
            const int pos = atomicAdd(&cntL, 1);
            g_pb[b][pos] = bv; g_pd[b][pos] = dv;
        }
    }
    #pragma unroll
    for (int off = 1; off < 64; off <<= 1) {
        mn = fminf(mn, __shfl_xor(mn, off, 64));
        mx = fmaxf(mx, __shfl_xor(mx, off, 64));
    }
    __syncthreads();
    if (lane == 0) { g_smin[b] = mn; g_smax[b] = mx; g_pcnt[b] = cntL; }
    // dmax + betti (H0)
    float dmax = -1.f;
    for (int s = lane; s < NROI - 1; s += 64) dmax = fmaxf(dmax, deaths[s]);
    #pragma unroll
    for (int off = 1; off < 64; off <<= 1) dmax = fmaxf(dmax, __shfl_xor(dmax, off, 64));
    const float stepg = dmax / 999.0f;       // f32 linspace step, start = 0
    for (int tt = lane; tt < RESN; tt += 64) {
        const float g = (tt == RESN - 1) ? dmax : (float)tt * stepg;
        int cnt2 = 0;
        for (int s2 = 0; s2 < NROI - 1; ++s2) cnt2 += (g < deaths[s2]) ? 1 : 0;
        g_betti[b * RESN + tt] = (float)cnt2;
    }
    if (lane == 0 && dmax > 0.f) atomicOr(&g_bnz, 1);
}

// ---------------- 6) persistence landscape: one wave per (b, grid point) ----------------
__global__ void __launch_bounds__(256) k_land(float* __restrict__ out) {
    const int wave = (blockIdx.x * blockDim.x + threadIdx.x) >> 6;
    const int lane = threadIdx.x & 63;
    const int b = wave / RESN, tt = wave % RESN;
    if (b >= NB) return;
    const int cnt = g_pcnt[b];
    const float smn = g_smin[b], smx = g_smax[b];
    const float stepg = (smx - smn) / 999.0f;
    const float g = (tt == RESN - 1) ? smx : smn + (float)tt * stepg;
    const float SQ2 = 1.41421356f;           // f32 sqrt(2), as reference
    float t5[5] = {0.f, 0.f, 0.f, 0.f, 0.f};
    const float* __restrict__ pb = g_pb[b];
    const float* __restrict__ pd = g_pd[b];
    for (int e = lane; e < cnt; e += 64) {
        float v = fminf(g - pb[e], pd[e] - g);
        v = v > 0.f ? v : 0.f;
        v *= SQ2;
        if (v > t5[4]) {
            t5[4] = v;
            #pragma unroll
            for (int z = 4; z > 0; --z)
                if (t5[z] > t5[z - 1]) { const float tmp = t5[z - 1]; t5[z - 1] = t5[z]; t5[z] = tmp; }
        }
    }
    // butterfly merge of sorted-desc top-5 lists
    for (int off = 1; off < 64; off <<= 1) {
        float bv[5];
        #pragma unroll
        for (int z = 0; z < 5; ++z) bv[z] = __shfl_xor(t5[z], off, 64);
        float o[5]; int ia = 0, ib = 0;
        #pragma unroll
        for (int z = 0; z < 5; ++z) {
            const bool ta = (ib >= 5) || (ia < 5 && t5[ia] >= bv[ib]);
            o[z] = ta ? t5[ia++] : bv[ib++];
        }
        #pragma unroll
        for (int z = 0; z < 5; ++z) t5[z] = o[z];
    }
    if (lane == 0) {
        const float land = (t5[0] + t5[1] + t5[2] + t5[3] + t5[4]) / 5.0f;
        for (int rep = 0; rep < BREP; ++rep)
            out[(rep * NB + b) * RESN + tt] = land;
    }
}

// ---------------- 7) orthonormal polynomial basis (skipped when betti==0) ----------------
__global__ void __launch_bounds__(1024) k_basis() {
    if (g_bnz == 0) return;   // degenerate H0 branch: fit is exactly zero, basis unused
    const int t = threadIdx.x;
    const int lane = t & 63, wv = t >> 6;  // 16 waves
    __shared__ double xs[RESN];
    __shared__ double w[RESN], dwv[RESN];
    __shared__ double cj[NMODE], ctot[NMODE];
    __shared__ double red[16];
    if (t < RESN) {
        xs[t] = (2.0 * (double)t - 999.0) / 999.0;
        const double q0 = 1.0 / sqrt(1000.0);
        g_q[0][t] = q0;
        g_qd[0][t] = 0.0;
    }
    __syncthreads();
    for (int k = 0; k < MDEG; ++k) {
        if (t < RESN) {
            w[t]   = xs[t] * g_q[k][t];
            dwv[t] = g_q[k][t] + xs[t] * g_qd[k][t];
        }
        if (t < NMODE) ctot[t] = 0.0;
        __syncthreads();
        for (int round = 0; round < 2; ++round) {   // CGS twice == stable
            for (int j = wv; j <= k; j += 16) {
                double p = 0.0;
                for (int tt = lane; tt < RESN; tt += 64) p += w[tt] * g_q[j][tt];
                p = wave_sum_f64(p);
                if (lane == 0) cj[j] = p;
            }
            __syncthreads();
            if (t < RESN) {
                double acc = w[t];
                for (int j = 0; j <= k; ++j) acc -= cj[j] * g_q[j][t];
                w[t] = acc;
            }
            if (t <= k) ctot[t] += cj[t];
            __syncthreads();
        }
        if (t < RESN) {
            double acc = dwv[t];
            for (int j = 0; j <= k; ++j) acc -= ctot[j] * g_qd[j][t];
            dwv[t] = acc;
        }
        double p = 0.0;
        for (int tt = t; tt < RESN; tt += 1024) p += w[tt] * w[tt];
        p = wave_sum_f64(p);
        if (lane == 0) red[wv] = p;
        __syncthreads();
        if (t == 0) {
            double s = 0.0;
            for (int z = 0; z < 16; ++z) s += red[z];
            red[0] = sqrt(s);
        }
        __syncthreads();
        const double beta = red[0];
        if (t < RESN) {
            g_q[k + 1][t]  = w[t] / beta;
            g_qd[k + 1][t] = dwv[t] / beta;
        }
        __syncthreads();
    }
}

// ---------------- 8) fit: project betti onto basis; emit yvals and |derivative|*scale ----------------
__global__ void __launch_bounds__(256) k_fit(float* __restrict__ out) {
    const int b = blockIdx.x, t = threadIdx.x;
    const int lane = t & 63, wv = t >> 6;  // 4 waves
    __shared__ double dk[NMODE];
    __shared__ float  bet[RESN];
    for (int tt = t; tt < RESN; tt += 256) bet[tt] = g_betti[b * RESN + tt];
    __syncthreads();
    for (int k = wv; k < NMODE; k += 4) {
        double p = 0.0;
        for (int tt = lane; tt < RESN; tt += 64) p += (double)bet[tt] * g_q[k][tt];
        p = wave_sum_f64(p);
        if (lane == 0) dk[k] = p;
    }
    __syncthreads();
    const double scale = 2.0 / 999.0;
    float* oy = out + BREP * NB * RESN;
    float* od = out + 2 * BREP * NB * RESN;
    for (int tt = t; tt < RESN; tt += 256) {
        double y = 0.0, d = 0.0;
        for (int k = 0; k < NMODE; ++k) {
            y += dk[k] * g_q[k][tt];
            d += dk[k] * g_qd[k][tt];
        }
        const float yv = (float)y;
        const float fd = (float)(fabs(d) * scale);
        for (int rep = 0; rep < BREP; ++rep) {
            oy[(rep * NB + b) * RESN + tt] = yv;
            if (tt >= SAMP && tt < RESN - SAMP)
                od[(rep * NB + b) * (RESN - 2 * SAMP) + (tt - SAMP)] = fd;
        }
    }
}

// ---------------- launcher ----------------
extern "C" void kernel_launch(void* const* d_in, const int* in_sizes, int n_in,
                              void* d_out, int out_size, void* d_ws, size_t ws_size,
                              hipStream_t stream) {
    const int*   ei  = (const int*)d_in[1];    // edge_index (2, 160000)
    const float* ea  = (const float*)d_in[2];  // edge_attr  (160000, 1)
    float*       out = (float*)d_out;          // [land 32x1000 | yvals 32x1000 | fderiv 32x900]

    k_zero<<<(NB * NROI * NROI + 255) / 256, 256, 0, stream>>>();
    k_scatter<<<(NEDGE + 255) / 256, 256, 0, stream>>>(ei, ea);
    k_transform<<<(NB * NROI * NROI + 255) / 256, 256, 0, stream>>>();
    k_death1<<<(NB * NROI * NROI + 255) / 256, 256, 0, stream>>>();
    k_prim<<<NB, 64, 0, stream>>>();
    k_land<<<(NB * RESN + 3) / 4, 256, 0, stream>>>(out);
    k_basis<<<1, 1024, 0, stream>>>();
    k_fit<<<NB, 256, 0, stream>>>(out);
}

// Round 3
// 162.721 us; speedup vs baseline: 32.8710x; 1.5284x over previous
//
#include <hip/hip_runtime.h>

// ---------------- problem constants ----------------
#define NROI  100
#define NB    4          // 400/100 diagonal blocks
#define NEDGE 160000
#define RESN  1000
#define SAMP  50
#define BREP  8          // batch tiling (B=8)
#define MDEG  44         // effective polynomial rank cutoff
#define NMODE (MDEG + 1)
#define BIGF  1.0e9f
#define PAIR_CAP 5056    // >= 100*99/2 - 99 masked pairs

// ---------------- static device workspace ----------------
__device__ float g_adj[NB * NROI * NROI];
__device__ float g_D[NB * NROI * NROI];
__device__ float g_death1[NB * NROI * NROI];
__device__ float g_betti[NB * RESN];
__device__ float g_pb[NB][PAIR_CAP];
__device__ float g_pd[NB][PAIR_CAP];
__device__ int   g_pcnt[NB];
__device__ float g_smin[NB], g_smax[NB];
__device__ int   g_bnz;              // any nonzero betti? (gates basis/fit)
__device__ double g_q[NMODE][RESN];  // orthonormal poly basis values
__device__ double g_qd[NMODE][RESN]; // derivatives d/dx

// ---------------- helpers ----------------
__device__ inline double wave_sum_f64(double p) {
    for (int off = 32; off > 0; off >>= 1) p += __shfl_xor(p, off, 64);
    return p;
}

// ---------------- 1) zero accumulators ----------------
__global__ void k_zero() {
    const int tid = blockIdx.x * blockDim.x + threadIdx.x;
    if (tid < NB * NROI * NROI) g_adj[tid] = 0.f;
    if (tid == 0) g_bnz = 0;
}

// ---------------- 2) scatter-add diagonal-block edges ----------------
__global__ void k_scatter(const int* __restrict__ ei, const float* __restrict__ ea) {
    const int e = blockIdx.x * blockDim.x + threadIdx.x;
    if (e >= NEDGE) return;
    const int r = ei[e], c = ei[NEDGE + e];
    const int br = r / NROI, bc = c / NROI;
    if (br == bc)
        atomicAdd(&g_adj[br * NROI * NROI + (r - br * NROI) * NROI + (c - bc * NROI)], ea[e]);
}

// ---------------- 3) D = max(1 - adj, 0) ----------------
__global__ void k_transform() {
    const int tid = blockIdx.x * blockDim.x + threadIdx.x;
    if (tid >= NB * NROI * NROI) return;
    const float d = 1.f - g_adj[tid];
    g_D[tid] = d > 0.f ? d : 0.f;
}

// ---------------- 4) H1 deaths: T[i,j] = min_k!=i,j max(D[i,k],D[j,k]); death1 = max(D,T) ----------------
// fmin/fmax are exact selections -> any association is bit-identical to the reference.
__global__ void k_death1() {
    const int tid = blockIdx.x * blockDim.x + threadIdx.x;
    if (tid >= NB * NROI * NROI) return;
    const int b  = tid / (NROI * NROI);
    const int ij = tid % (NROI * NROI);
    const int i = ij / NROI, j = ij % NROI;
    const float* __restrict__ ri = g_D + b * NROI * NROI + i * NROI;
    const float* __restrict__ rj = g_D + b * NROI * NROI + j * NROI;
    float Tm = BIGF;
    for (int k = 0; k < NROI; k += 4) {
        const float4 a = *(const float4*)(ri + k);
        const float4 c = *(const float4*)(rj + k);
        float m0 = (k + 0 == i || k + 0 == j) ? BIGF : fmaxf(a.x, c.x);
        float m1 = (k + 1 == i || k + 1 == j) ? BIGF : fmaxf(a.y, c.y);
        float m2 = (k + 2 == i || k + 2 == j) ? BIGF : fmaxf(a.z, c.z);
        float m3 = (k + 3 == i || k + 3 == j) ? BIGF : fmaxf(a.w, c.w);
        Tm = fminf(Tm, fminf(fminf(m0, m1), fminf(m2, m3)));
    }
    g_death1[tid] = fmaxf(ri[j], Tm);
}

// ---------------- 5) single-wave Prim, LDS-resident D, ballot zero fast path ----------------
__global__ void __launch_bounds__(64) k_prim() {
    const int b = blockIdx.x, lane = threadIdx.x;
    const float* __restrict__ Db = g_D + b * NROI * NROI;
    __shared__ float Dl[NROI * NROI];
    __shared__ float deaths[NROI - 1];
    __shared__ int   parL[NROI];
    __shared__ unsigned char mstL[NROI * NROI];
    __shared__ int cntL;
    // stage D into LDS (2500 float4)
    for (int i = lane; i < NROI * NROI / 4; i += 64)
        ((float4*)Dl)[i] = ((const float4*)Db)[i];
    for (int e = lane; e < NROI * NROI; e += 64) mstL[e] = 0;
    if (lane < NROI) parL[lane] = 0;
    if (lane == 0) cntL = 0;
    __syncthreads();

    const int i1 = 64 + lane;
    const bool has1 = (i1 < NROI);
    float mind0 = Dl[lane];                 // D[0][lane]
    float mind1 = has1 ? Dl[i1] : BIGF;
    bool in0 = (lane == 0), in1 = false;

    for (int step = 0; step < NROI - 1; ++step) {
        // fast path: D >= 0 always, so if any frontier value is exactly 0,
        // jnp.argmin == first not-in-tree index with mind == 0 -> one ballot.
        const bool z0 = (!in0) && (mind0 == 0.f);
        const unsigned long long m0 = __ballot(z0);
        int j; float v;
        if (m0) {
            j = __ffsll(m0) - 1; v = 0.f;
        } else {
            const bool z1 = has1 && (!in1) && (mind1 == 0.f);
            const unsigned long long m1 = __ballot(z1);
            if (m1) {
                j = 64 + __ffsll(m1) - 1; v = 0.f;
            } else {
                // exact first-index argmin fallback (general data)
                float v0 = in0 ? BIGF : mind0;
                float v1 = (has1 && !in1) ? mind1 : BIGF;
                float vv; int idx;
                if (v0 <= v1) { vv = v0; idx = lane; } else { vv = v1; idx = i1; }
                #pragma unroll
                for (int off = 1; off < 64; off <<= 1) {
                    const float ov = __shfl_xor(vv, off, 64);
                    const int   oi = __shfl_xor(idx, off, 64);
                    if (ov < vv || (ov == vv && oi < idx)) { vv = ov; idx = oi; }
                }
                j = idx; v = vv;
            }
        }
        if (lane == 0) {                    // record (off the critical path)
            deaths[step] = v;
            const int u = parL[j];
            mstL[u * NROI + j] = 1;
            mstL[j * NROI + u] = 1;
        }
        if (lane == j) in0 = true;
        if (i1 == j)   in1 = true;
        const float dj0 = Dl[j * NROI + lane];
        if (!in0 && dj0 < mind0) { mind0 = dj0; parL[lane] = j; }  // strict <, as reference
        if (has1) {
            const float dj1 = Dl[j * NROI + i1];
            if (!in1 && dj1 < mind1) { mind1 = dj1; parL[i1] = j; }
        }
    }
    __syncthreads();

    // masked pair compaction + smin/smax
    float mn = BIGF, mx = -BIGF;
    for (int e = lane; e < NROI * NROI; e += 64) {
        const int i = e / NROI, jj = e % NROI;
        if (i < jj && !mstL[e]) {
            const float bv = Dl[e];
            const float dv = g_death1[b * NROI * NROI + e];
            mn = fminf(mn, bv); mx = fmaxf(mx, dv);
            const int pos = atomicAdd(&cntL, 1);
            g_pb[b][pos] = bv; g_pd[b][pos] = dv;
        }
    }
    #pragma unroll
    for (int off = 1; off < 64; off <<= 1) {
        mn = fminf(mn, __shfl_xor(mn, off, 64));
        mx = fmaxf(mx, __shfl_xor(mx, off, 64));
    }
    __syncthreads();
    if (lane == 0) { g_smin[b] = mn; g_smax[b] = mx; g_pcnt[b] = cntL; }

    // dmax + betti (H0)
    float dmax = -1.f;
    for (int s = lane; s < NROI - 1; s += 64) dmax = fmaxf(dmax, deaths[s]);
    #pragma unroll
    for (int off = 1; off < 64; off <<= 1) dmax = fmaxf(dmax, __shfl_xor(dmax, off, 64));
    const float stepg = dmax / 999.0f;       // f32 linspace step, start = 0
    for (int tt = lane; tt < RESN; tt += 64) {
        const float g = (tt == RESN - 1) ? dmax : (float)tt * stepg;
        int cnt2 = 0;
        for (int s2 = 0; s2 < NROI - 1; ++s2) cnt2 += (g < deaths[s2]) ? 1 : 0;
        g_betti[b * RESN + tt] = (float)cnt2;
    }
    if (lane == 0 && dmax > 0.f) atomicOr(&g_bnz, 1);
}

// ---------------- 6) persistence landscape: one wave per (b, grid point) ----------------
__global__ void __launch_bounds__(256) k_land(float* __restrict__ out) {
    const int wave = (blockIdx.x * blockDim.x + threadIdx.x) >> 6;
    const int lane = threadIdx.x & 63;
    const int b = wave / RESN, tt = wave % RESN;
    if (b >= NB) return;
    const int cnt = g_pcnt[b];
    const float smn = g_smin[b], smx = g_smax[b];
    const float stepg = (smx - smn) / 999.0f;
    const float g = (tt == RESN - 1) ? smx : smn + (float)tt * stepg;
    const float SQ2 = 1.41421356f;           // f32 sqrt(2), as reference
    float t5[5] = {0.f, 0.f, 0.f, 0.f, 0.f};
    const float* __restrict__ pb = g_pb[b];
    const float* __restrict__ pd = g_pd[b];
    for (int e = lane; e < cnt; e += 64) {
        float v = fminf(g - pb[e], pd[e] - g);
        v = v > 0.f ? v : 0.f;
        v *= SQ2;
        if (v > t5[4]) {
            t5[4] = v;
            #pragma unroll
            for (int z = 4; z > 0; --z)
                if (t5[z] > t5[z - 1]) { const float tmp = t5[z - 1]; t5[z - 1] = t5[z]; t5[z] = tmp; }
        }
    }
    // butterfly merge of sorted-desc top-5 lists
    for (int off = 1; off < 64; off <<= 1) {
        float bv[5];
        #pragma unroll
        for (int z = 0; z < 5; ++z) bv[z] = __shfl_xor(t5[z], off, 64);
        float o[5]; int ia = 0, ib = 0;
        #pragma unroll
        for (int z = 0; z < 5; ++z) {
            const bool ta = (ib >= 5) || (ia < 5 && t5[ia] >= bv[ib]);
            o[z] = ta ? t5[ia++] : bv[ib++];
        }
        #pragma unroll
        for (int z = 0; z < 5; ++z) t5[z] = o[z];
    }
    if (lane == 0) {
        const float land = (t5[0] + t5[1] + t5[2] + t5[3] + t5[4]) / 5.0f;
        for (int rep = 0; rep < BREP; ++rep)
            out[(rep * NB + b) * RESN + tt] = land;
    }
}

// ---------------- 7) orthonormal polynomial basis (skipped when betti==0) ----------------
__global__ void __launch_bounds__(1024) k_basis() {
    if (g_bnz == 0) return;   // degenerate H0 branch: fit is exactly zero, basis unused
    const int t = threadIdx.x;
    const int lane = t & 63, wv = t >> 6;  // 16 waves
    __shared__ double xs[RESN];
    __shared__ double w[RESN], dwv[RESN];
    __shared__ double cj[NMODE], ctot[NMODE];
    __shared__ double red[16];
    if (t < RESN) {
        xs[t] = (2.0 * (double)t - 999.0) / 999.0;
        const double q0 = 1.0 / sqrt(1000.0);
        g_q[0][t] = q0;
        g_qd[0][t] = 0.0;
    }
    __syncthreads();
    for (int k = 0; k < MDEG; ++k) {
        if (t < RESN) {
            w[t]   = xs[t] * g_q[k][t];
            dwv[t] = g_q[k][t] + xs[t] * g_qd[k][t];
        }
        if (t < NMODE) ctot[t] = 0.0;
        __syncthreads();
        for (int round = 0; round < 2; ++round) {   // CGS twice == stable
            for (int j = wv; j <= k; j += 16) {
                double p = 0.0;
                for (int tt = lane; tt < RESN; tt += 64) p += w[tt] * g_q[j][tt];
                p = wave_sum_f64(p);
                if (lane == 0) cj[j] = p;
            }
            __syncthreads();
            if (t < RESN) {
                double acc = w[t];
                for (int j = 0; j <= k; ++j) acc -= cj[j] * g_q[j][t];
                w[t] = acc;
            }
            if (t <= k) ctot[t] += cj[t];
            __syncthreads();
        }
        if (t < RESN) {
            double acc = dwv[t];
            for (int j = 0; j <= k; ++j) acc -= ctot[j] * g_qd[j][t];
            dwv[t] = acc;
        }
        double p = 0.0;
        for (int tt = t; tt < RESN; tt += 1024) p += w[tt] * w[tt];
        p = wave_sum_f64(p);
        if (lane == 0) red[wv] = p;
        __syncthreads();
        if (t == 0) {
            double s = 0.0;
            for (int z = 0; z < 16; ++z) s += red[z];
            red[0] = sqrt(s);
        }
        __syncthreads();
        const double beta = red[0];
        if (t < RESN) {
            g_q[k + 1][t]  = w[t] / beta;
            g_qd[k + 1][t] = dwv[t] / beta;
        }
        __syncthreads();
    }
}

// ---------------- 8) fit: project betti onto basis; emit yvals and |derivative|*scale ----------------
__global__ void __launch_bounds__(256) k_fit(float* __restrict__ out) {
    const int b = blockIdx.x, t = threadIdx.x;
    float* oy = out + BREP * NB * RESN;
    float* od = out + 2 * BREP * NB * RESN;
    if (g_bnz == 0) {
        // betti == 0 everywhere -> coef == 0 -> yvals/fderiv exactly 0
        for (int tt = t; tt < RESN; tt += 256) {
            for (int rep = 0; rep < BREP; ++rep) {
                oy[(rep * NB + b) * RESN + tt] = 0.f;
                if (tt >= SAMP && tt < RESN - SAMP)
                    od[(rep * NB + b) * (RESN - 2 * SAMP) + (tt - SAMP)] = 0.f;
            }
        }
        return;
    }
    const int lane = t & 63, wv = t >> 6;  // 4 waves
    __shared__ double dk[NMODE];
    __shared__ float  bet[RESN];
    for (int tt = t; tt < RESN; tt += 256) bet[tt] = g_betti[b * RESN + tt];
    __syncthreads();
    for (int k = wv; k < NMODE; k += 4) {
        double p = 0.0;
        for (int tt = lane; tt < RESN; tt += 64) p += (double)bet[tt] * g_q[k][tt];
        p = wave_sum_f64(p);
        if (lane == 0) dk[k] = p;
    }
    __syncthreads();
    const double scale = 2.0 / 999.0;
    for (int tt = t; tt < RESN; tt += 256) {
        double y = 0.0, d = 0.0;
        for (int k = 0; k < NMODE; ++k) {
            y += dk[k] * g_q[k][tt];
            d += dk[k] * g_qd[k][tt];
        }
        const float yv = (float)y;
        const float fd = (float)(fabs(d) * scale);
        for (int rep = 0; rep < BREP; ++rep) {
            oy[(rep * NB + b) * RESN + tt] = yv;
            if (tt >= SAMP && tt < RESN - SAMP)
                od[(rep * NB + b) * (RESN - 2 * SAMP) + (tt - SAMP)] = fd;
        }
    }
}

// ---------------- launcher ----------------
extern "C" void kernel_launch(void* const* d_in, const int* in_sizes, int n_in,
                              void* d_out, int out_size, void* d_ws, size_t ws_size,
                              hipStream_t stream) {
    const int*   ei  = (const int*)d_in[1];    // edge_index (2, 160000)
    const float* ea  = (const float*)d_in[2];  // edge_attr  (160000, 1)
    float*       out = (float*)d_out;          // [land 32x1000 | yvals 32x1000 | fderiv 32x900]

    k_zero<<<(NB * NROI * NROI + 255) / 256, 256, 0, stream>>>();
    k_scatter<<<(NEDGE + 255) / 256, 256, 0, stream>>>(ei, ea);
    k_transform<<<(NB * NROI * NROI + 255) / 256, 256, 0, stream>>>();
    k_death1<<<(NB * NROI * NROI + 255) / 256, 256, 0, stream>>>();
    k_prim<<<NB, 64, 0, stream>>>();
    k_land<<<(NB * RESN + 3) / 4, 256, 0, stream>>>(out);
    k_basis<<<1, 1024, 0, stream>>>();
    k_fit<<<NB, 256, 0, stream>>>(out);
}